// Round 1
// baseline (49.202 us; speedup 1.0000x reference)
//
#include <hip/hip_runtime.h>

// QME loss: mean over B of 2*(|p1*t1| + |p2*t2| + |p3*t3|)
// (abs makes the conj sign flip irrelevant)
// Pure streaming reduction: 268 MB read, 4 B write -> HBM-bound.

__global__ void qme_partial(const float4* __restrict__ pred,
                            const float4* __restrict__ tru,
                            float* __restrict__ partial, int n) {
    int tid = blockIdx.x * blockDim.x + threadIdx.x;
    int stride = gridDim.x * blockDim.x;
    float acc = 0.0f;
    for (int i = tid; i < n; i += stride) {
        float4 p = pred[i];
        float4 t = tru[i];
        acc += fabsf(p.y * t.y) + fabsf(p.z * t.z) + fabsf(p.w * t.w);
    }
    // wave-64 shuffle reduce
    #pragma unroll
    for (int off = 32; off > 0; off >>= 1)
        acc += __shfl_down(acc, off, 64);
    __shared__ float lds[4];  // 256 threads = 4 waves
    int wave = threadIdx.x >> 6;
    if ((threadIdx.x & 63) == 0) lds[wave] = acc;
    __syncthreads();
    if (threadIdx.x == 0)
        partial[blockIdx.x] = lds[0] + lds[1] + lds[2] + lds[3];
}

__global__ void qme_final(const float* __restrict__ partial, int nblocks,
                          float* __restrict__ out, float scale) {
    float acc = 0.0f;
    for (int i = threadIdx.x; i < nblocks; i += blockDim.x)
        acc += partial[i];
    #pragma unroll
    for (int off = 32; off > 0; off >>= 1)
        acc += __shfl_down(acc, off, 64);
    __shared__ float lds[4];
    int wave = threadIdx.x >> 6;
    if ((threadIdx.x & 63) == 0) lds[wave] = acc;
    __syncthreads();
    if (threadIdx.x == 0)
        out[0] = (lds[0] + lds[1] + lds[2] + lds[3]) * scale;
}

extern "C" void kernel_launch(void* const* d_in, const int* in_sizes, int n_in,
                              void* d_out, int out_size, void* d_ws, size_t ws_size,
                              hipStream_t stream) {
    const float4* pred = (const float4*)d_in[0];
    const float4* tru  = (const float4*)d_in[1];
    float* out = (float*)d_out;
    float* partial = (float*)d_ws;

    int n = in_sizes[0] / 4;          // number of quaternions (8388608)
    const int threads = 256;
    const int blocks = 2048;          // 256 CUs x 8 blocks/CU, grid-stride covers rest

    qme_partial<<<blocks, threads, 0, stream>>>(pred, tru, partial, n);
    qme_final<<<1, 256, 0, stream>>>(partial, blocks, out, 2.0f / (float)n);
}

// Round 2
// 49.129 us; speedup vs baseline: 1.0015x; 1.0015x over previous
//
#include <hip/hip_runtime.h>

// QME loss: mean over B of 2*(|p1*t1| + |p2*t2| + |p3*t3|)
// Streaming reduction: 268 MB read, 4 B write. Partially L3-resident across
// replays (FETCH ~134 MB), so deepen MLP with 4x unroll (8 loads in flight)
// to push past the latency-limited ~5.5 TB/s.

__global__ void qme_partial(const float4* __restrict__ pred,
                            const float4* __restrict__ tru,
                            float* __restrict__ partial, int n) {
    int tid = blockIdx.x * blockDim.x + threadIdx.x;
    int S = gridDim.x * blockDim.x;
    float acc = 0.0f;
    int i = tid;
    // unrolled x4: issue all 8 loads before any dependent math
    for (; i + 3 * S < n; i += 4 * S) {
        float4 p0 = pred[i];
        float4 p1 = pred[i + S];
        float4 p2 = pred[i + 2 * S];
        float4 p3 = pred[i + 3 * S];
        float4 t0 = tru[i];
        float4 t1 = tru[i + S];
        float4 t2 = tru[i + 2 * S];
        float4 t3 = tru[i + 3 * S];
        acc += fabsf(p0.y * t0.y) + fabsf(p0.z * t0.z) + fabsf(p0.w * t0.w);
        acc += fabsf(p1.y * t1.y) + fabsf(p1.z * t1.z) + fabsf(p1.w * t1.w);
        acc += fabsf(p2.y * t2.y) + fabsf(p2.z * t2.z) + fabsf(p2.w * t2.w);
        acc += fabsf(p3.y * t3.y) + fabsf(p3.z * t3.z) + fabsf(p3.w * t3.w);
    }
    for (; i < n; i += S) {
        float4 p = pred[i];
        float4 t = tru[i];
        acc += fabsf(p.y * t.y) + fabsf(p.z * t.z) + fabsf(p.w * t.w);
    }
    // wave-64 shuffle reduce
    #pragma unroll
    for (int off = 32; off > 0; off >>= 1)
        acc += __shfl_down(acc, off, 64);
    __shared__ float lds[4];  // 256 threads = 4 waves
    int wave = threadIdx.x >> 6;
    if ((threadIdx.x & 63) == 0) lds[wave] = acc;
    __syncthreads();
    if (threadIdx.x == 0)
        partial[blockIdx.x] = lds[0] + lds[1] + lds[2] + lds[3];
}

__global__ void qme_final(const float* __restrict__ partial, int nblocks,
                          float* __restrict__ out, float scale) {
    float acc = 0.0f;
    for (int i = threadIdx.x; i < nblocks; i += blockDim.x)
        acc += partial[i];
    #pragma unroll
    for (int off = 32; off > 0; off >>= 1)
        acc += __shfl_down(acc, off, 64);
    __shared__ float lds[4];
    int wave = threadIdx.x >> 6;
    if ((threadIdx.x & 63) == 0) lds[wave] = acc;
    __syncthreads();
    if (threadIdx.x == 0)
        out[0] = (lds[0] + lds[1] + lds[2] + lds[3]) * scale;
}

extern "C" void kernel_launch(void* const* d_in, const int* in_sizes, int n_in,
                              void* d_out, int out_size, void* d_ws, size_t ws_size,
                              hipStream_t stream) {
    const float4* pred = (const float4*)d_in[0];
    const float4* tru  = (const float4*)d_in[1];
    float* out = (float*)d_out;
    float* partial = (float*)d_ws;

    int n = in_sizes[0] / 4;          // number of quaternions (8388608)
    const int threads = 256;
    const int blocks = 2048;          // 256 CUs x 8 blocks/CU, fully co-resident

    qme_partial<<<blocks, threads, 0, stream>>>(pred, tru, partial, n);
    qme_final<<<1, 256, 0, stream>>>(partial, blocks, out, 2.0f / (float)n);
}